// Round 11
// baseline (1038.325 us; speedup 1.0000x reference)
//
#include <hip/hip_runtime.h>
#include <hip/hip_bf16.h>

#define M_DIM 8192      // B*S = 4*2048
#define K_DIM 4096
#define N_DIM 16384

#define BK 64
#define NT (K_DIM / BK)   // 64 K-tiles

typedef __attribute__((ext_vector_type(8))) short bf16x8;
typedef __attribute__((ext_vector_type(4))) float f32x4;
typedef __attribute__((ext_vector_type(4))) unsigned short u16x4;

__device__ __forceinline__ unsigned short f2bf(float f) {
  unsigned int u = __builtin_bit_cast(unsigned int, f);
  u += 0x7fffu + ((u >> 16) & 1u);     // RNE
  return (unsigned short)(u >> 16);
}

__global__ void cvt_kernel(const float* __restrict__ src,
                           unsigned short* __restrict__ dst, int n4) {
  int i = blockIdx.x * blockDim.x + threadIdx.x;
  int stride = gridDim.x * blockDim.x;
  for (; i < n4; i += stride) {
    f32x4 v = __builtin_nontemporal_load(&((const f32x4*)src)[i]);
    u16x4 o;
    o.x = f2bf(v.x); o.y = f2bf(v.y); o.z = f2bf(v.z); o.w = f2bf(v.w);
    ((u16x4*)dst)[i] = o;
  }
}

__device__ __forceinline__ void gload_lds16(const void* g, void* lds) {
  __builtin_amdgcn_global_load_lds(
      (const __attribute__((address_space(1))) unsigned int*)g,
      (__attribute__((address_space(3))) unsigned int*)lds, 16, 0, 0);
}

// ============================================================================
// ROUND 11: TWO-BLOCKS-PER-CU, maximally simple schedule (m114/m97 cross-
// block overlap mechanism). Rationale: 5 passing 1-block/CU schedules all hit
// 51-54% MfmaUtil because block-wide barriers make the LDS-read pipe
// (2304 cyc/CU/tile) and MFMA pipe (2483 cyc/SIMD/tile) ADDITIVE. Two
// independent 4-wave blocks share no barriers -> one block's MFMA covers the
// other's stage/drain/read phases.
// Geometry: tile 128x256, 4 waves (2M x 2N), wave-tile 64x128, acc[4][8]
// (128 regs). LDS: lA 16KB + lB 32KB = 48KB STATIC, single-buffered ->
// 2 blocks/CU by LDS(96KB) and VGPR (~244 unified -> 2 waves/SIMD).
// Per K-tile (NO counted waits, NO hand asm, NO slot lifetimes):
//   stage A(u) 4 gloads + B(u) 8 gloads  (per wave)
//   __syncthreads()   // full vmcnt/lgkm drain + barrier (compiler-emitted)
//   kk=0: 12 ds_reads + 32 MFMA; kk=1: same  (compiler-tracked lgkm waits)
//   __syncthreads()   // seals reads before next tile's stage overwrites
// Stage and read are NEVER concurrent -> zero race surface.
// Fragment swizzle (verified r2-r8): phys 16B block = logical ^ (row&7);
// linear LDS dest + inverse-swizzled GLOBAL source (rule #21).
// XCD map: 8 bm-rows per XCD, (bno:8)x(bmi:8)x(bni:8) order -> ~64 resident
// blocks/XCD form 8bm x 8bn panel windows.
// Epilogue: r2-style plain scalar stores (proven; WRITE was clean 524MB).
// ============================================================================
__global__ __launch_bounds__(256, 2) void gemm2b(const short* __restrict__ A,
                                                 const short* __restrict__ Bm,
                                                 const float* __restrict__ bias,
                                                 float* __restrict__ C) {
  __shared__ short lA[128 * 64];   // 16 KB
  __shared__ short lB[256 * 64];   // 32 KB

  const int tid = threadIdx.x;
  const int w = tid >> 6, l = tid & 63;   // 4 waves
  const int wr = w >> 1;     // 0..1  (M half: 64 rows)
  const int wc = w & 1;      // 0..1  (N half: 128 cols)
  const int fr = l & 15;     // fragment row/col
  const int kq = l >> 4;     // k quarter
  const int sr = l >> 3;     // staging row-in-8
  const int sb = (l & 7) ^ sr;  // inverse-swizzled source block
  const int x7 = (fr & 7) << 3;

  // ---- XCD 2D tile map: 4096 blocks = 8 XCDs x (8 bno x 8 bmi x 8 bni) ----
  const int bid = blockIdx.x;
  const int chunk = bid & 7;
  const int local = bid >> 3;          // 0..511
  const int bni = local & 7;
  const int bmi = (local >> 3) & 7;
  const int bno = local >> 6;          // 0..7
  const int bm = chunk * 8 + bmi;      // 0..63  (M/128)
  const int bn = bno * 8 + bni;        // 0..63  (N/256)
  const size_t m0 = (size_t)bm * 128, n0 = (size_t)bn * 256;

  const short* Abase = A + m0 * K_DIM;
  const short* Bbase = Bm + n0 * K_DIM;

  f32x4 acc[4][8];
#pragma unroll
  for (int mi = 0; mi < 4; ++mi)
#pragma unroll
    for (int ni = 0; ni < 8; ++ni) acc[mi][ni] = (f32x4){0.f, 0.f, 0.f, 0.f};

  float bv[8];
#pragma unroll
  for (int ni = 0; ni < 8; ++ni) bv[ni] = bias[n0 + wc * 128 + ni * 16 + fr];

#pragma unroll 1
  for (int u = 0; u < NT; ++u) {
    const size_t ko = (size_t)u * BK;
    // ---- stage tile u: A 128 rows (4 gloads/wave), B 256 rows (8) ----
#pragma unroll
    for (int i = 0; i < 4; ++i) {
      const short* src = Abase + (size_t)(32 * i + w * 8 + sr) * K_DIM + ko + sb * 8;
      gload_lds16(src, &lA[(32 * i + w * 8) * 64]);
    }
#pragma unroll
    for (int i = 0; i < 8; ++i) {
      const short* src = Bbase + (size_t)(32 * i + w * 8 + sr) * K_DIM + ko + sb * 8;
      gload_lds16(src, &lB[(32 * i + w * 8) * 64]);
    }
    __syncthreads();   // full drain (vmcnt0+lgkm0) + barrier: tile landed

    // ---- compute: kk-split to cap register liveness (~200 regs) ----
#pragma unroll
    for (int kk = 0; kk < 2; ++kk) {
      bf16x8 af[4], bf[8];
      const int off = (kk * 32 + kq * 8);
#pragma unroll
      for (int mi = 0; mi < 4; ++mi)
        af[mi] = *(const bf16x8*)&lA[(wr * 64 + mi * 16 + fr) * 64 + (off ^ x7)];
#pragma unroll
      for (int ni = 0; ni < 8; ++ni)
        bf[ni] = *(const bf16x8*)&lB[(wc * 128 + ni * 16 + fr) * 64 + (off ^ x7)];
      __builtin_amdgcn_s_setprio(1);
#pragma unroll
      for (int mi = 0; mi < 4; ++mi)
#pragma unroll
        for (int ni = 0; ni < 8; ++ni)
          acc[mi][ni] = __builtin_amdgcn_mfma_f32_16x16x32_bf16(
              af[mi], bf[ni], acc[mi][ni], 0, 0, 0);
      __builtin_amdgcn_s_setprio(0);
    }
    __syncthreads();   // seals all reads before next tile's stage
  }

  // ---- epilogue: plain scalar stores (r2-proven) ----
  const int crow0 = kq * 4;
#pragma unroll
  for (int mi = 0; mi < 4; ++mi) {
#pragma unroll
    for (int ni = 0; ni < 8; ++ni) {
      f32x4 v = acc[mi][ni];
      size_t col = n0 + wc * 128 + ni * 16 + fr;
      size_t rb = m0 + (size_t)wr * 64 + mi * 16 + crow0;
#pragma unroll
      for (int j = 0; j < 4; ++j) C[(rb + j) * N_DIM + col] = v[j] + bv[ni];
    }
  }
}

// ---- fallback (ws too small): 128^2 kernel, fp32 in, reg-staged ----
__global__ __launch_bounds__(256) void gemm_f32(const float* __restrict__ Af,
                                                const float* __restrict__ Bf,
                                                const float* __restrict__ bias,
                                                float* __restrict__ C) {
  __shared__ short lA[128 * 64];
  __shared__ short lB[128 * 64];
  const int tid = threadIdx.x;
  const int w = tid >> 6, l = tid & 63;
  const int wr = w >> 1, wc = w & 1;
  int bid = blockIdx.x;
  int cpx = (M_DIM / 128) * (N_DIM / 128) / 8;
  int swz = (bid & 7) * cpx + (bid >> 3);
  const int bm = swz / (N_DIM / 128);
  const int bn = swz % (N_DIM / 128);
  const size_t m0 = (size_t)bm * 128, n0 = (size_t)bn * 128;
  const int lr = l >> 3, fr = l & 15, kq = l >> 4;

  f32x4 acc[4][4];
#pragma unroll
  for (int mi = 0; mi < 4; ++mi)
#pragma unroll
    for (int ni = 0; ni < 4; ++ni) acc[mi][ni] = (f32x4){0.f, 0.f, 0.f, 0.f};
  float bv[4];
#pragma unroll
  for (int ni = 0; ni < 4; ++ni) bv[ni] = bias[n0 + 64 * wc + 16 * ni + fr];

  for (int kt = 0; kt < K_DIM; kt += 64) {
    const float* Ab = Af + m0 * K_DIM + kt;
    const float* Bb = Bf + n0 * K_DIM + kt;
#pragma unroll
    for (int i = 0; i < 4; ++i) {
      int row = 32 * i + 8 * w + lr;
      int dsoff = row * 64 + ((8 * (l & 7)) ^ (lr << 3));
      f32x4 a0 = *(const f32x4*)(Ab + (size_t)row * K_DIM + 8 * (l & 7));
      f32x4 a1 = *(const f32x4*)(Ab + (size_t)row * K_DIM + 8 * (l & 7) + 4);
      bf16x8 ra;
#pragma unroll
      for (int j = 0; j < 4; ++j) { ra[j] = (short)f2bf(a0[j]); ra[j + 4] = (short)f2bf(a1[j]); }
      *(bf16x8*)&lA[dsoff] = ra;
      f32x4 b0 = *(const f32x4*)(Bb + (size_t)row * K_DIM + 8 * (l & 7));
      f32x4 b1 = *(const f32x4*)(Bb + (size_t)row * K_DIM + 8 * (l & 7) + 4);
      bf16x8 rb;
#pragma unroll
      for (int j = 0; j < 4; ++j) { rb[j] = (short)f2bf(b0[j]); rb[j + 4] = (short)f2bf(b1[j]); }
      *(bf16x8*)&lB[dsoff] = rb;
    }
    __syncthreads();
#pragma unroll
    for (int kk = 0; kk < 64; kk += 32) {
      bf16x8 af[4], bf_[4];
#pragma unroll
      for (int mi = 0; mi < 4; ++mi)
        af[mi] = *(const bf16x8*)&lA[(64 * wr + 16 * mi + fr) * 64 +
                                     ((kk + 8 * kq) ^ ((fr & 7) << 3))];
#pragma unroll
      for (int ni = 0; ni < 4; ++ni)
        bf_[ni] = *(const bf16x8*)&lB[(64 * wc + 16 * ni + fr) * 64 +
                                      ((kk + 8 * kq) ^ ((fr & 7) << 3))];
#pragma unroll
      for (int mi = 0; mi < 4; ++mi)
#pragma unroll
        for (int ni = 0; ni < 4; ++ni)
          acc[mi][ni] = __builtin_amdgcn_mfma_f32_16x16x32_bf16(
              af[mi], bf_[ni], acc[mi][ni], 0, 0, 0);
    }
    __syncthreads();
  }
  const int crow0 = kq * 4;
#pragma unroll
  for (int mi = 0; mi < 4; ++mi)
#pragma unroll
    for (int ni = 0; ni < 4; ++ni) {
      f32x4 v = acc[mi][ni];
      size_t col = n0 + 64 * wc + 16 * ni + fr;
      size_t rb = m0 + 64 * wr + 16 * mi + crow0;
#pragma unroll
      for (int j = 0; j < 4; ++j) C[(rb + j) * N_DIM + col] = v[j] + bv[ni];
    }
}

extern "C" void kernel_launch(void* const* d_in, const int* in_sizes, int n_in,
                              void* d_out, int out_size, void* d_ws, size_t ws_size,
                              hipStream_t stream) {
  const float* x = (const float*)d_in[0];     // [8192][4096]
  const float* W = (const float*)d_in[1];     // [16384][4096]
  const float* bias = (const float*)d_in[2];  // [16384]
  float* out = (float*)d_out;

  const size_t nA = (size_t)M_DIM * K_DIM;
  const size_t nB = (size_t)N_DIM * K_DIM;
  const size_t need = (nA + nB) * sizeof(unsigned short);  // 192 MB

  if (ws_size >= need) {
    unsigned short* wsA = (unsigned short*)d_ws;
    unsigned short* wsB = wsA + nA;
    cvt_kernel<<<4096, 256, 0, stream>>>(x, wsA, (int)(nA / 4));
    cvt_kernel<<<4096, 256, 0, stream>>>(W, wsB, (int)(nB / 4));
    const int nblk = (M_DIM / 128) * (N_DIM / 256);  // 4096
    gemm2b<<<nblk, 256, 0, stream>>>((const short*)wsA, (const short*)wsB,
                                     bias, out);
  } else {
    const int nblk = (M_DIM / 128) * (N_DIM / 128);  // 8192
    gemm_f32<<<nblk, 256, 0, stream>>>(x, W, bias, out);
  }
}